// Round 4
// baseline (56.516 us; speedup 1.0000x reference)
//
#include <hip/hip_runtime.h>

#define IMG   224
#define IMG2  (IMG*IMG)
#define NN    27          // patches per dim
#define KK    256         // pixels per patch
#define EE    128
#define NPAIR 14          // pairs of 8-row output strips

typedef float f32x4 __attribute__((ext_vector_type(4)));
typedef short s16x8 __attribute__((ext_vector_type(8)));

__device__ __forceinline__ unsigned short f2bf(float f) {
    unsigned int u = __float_as_uint(f);
    u = (u + 0x7fffu + ((u >> 16) & 1u)) >> 16;   // RNE (inputs finite)
    return (unsigned short)u;
}
__device__ __forceinline__ float bf2f(unsigned short u) {
    return __uint_as_float((unsigned int)u << 16);
}

// M[c][k][j] = sum_e W_dec[c][k][e]*W_enc[c][e][j], packed in MFMA A-frag order:
// APK[c][kf(16)][jb(8)][lane(64)][i(8)] = bf16(M[kf*16+(lane&15)][jb*32+8*(lane>>4)+i])
// Also v[c][k] = b_dec[c][k] + sum_e W_dec[c][k][e]*b_enc[c][e].
__global__ void pack_M(const float* __restrict__ W_enc, const float* __restrict__ W_dec,
                       const float* __restrict__ b_enc, const float* __restrict__ b_dec,
                       unsigned short* __restrict__ APK, float* __restrict__ v) {
    int k = blockIdx.x, c = blockIdx.y, j = threadIdx.x;
    const float* wd = W_dec + ((size_t)c*KK + k)*EE;
    const float* we = W_enc + (size_t)c*EE*KK + j;
    float acc = 0.f;
    #pragma unroll 8
    for (int e = 0; e < EE; ++e) acc = fmaf(wd[e], we[(size_t)e*KK], acc);
    int kf = k >> 4, kr = k & 15, jb = j >> 5, g = (j >> 3) & 3, i = j & 7;
    APK[(size_t)c*65536 + (((kf*8 + jb)*64) + g*16 + kr)*8 + i] = f2bf(acc);

    __shared__ float pv[128];
    if (j < EE) pv[j] = wd[j] * b_enc[c*EE + j];
    __syncthreads();
    for (int off = 64; off > 0; off >>= 1) {
        if (j < off) pv[j] += pv[j + off];
        __syncthreads();
    }
    if (j == 0) v[c*KK + k] = pv[0] + b_dec[c*KK + k];
}

// Block = strips (2t, 2t+1) of one (b,c). Wave (prow,kq) reuses its A-frags for both strips:
//   prow0 (k 0..127, top halves):  ny=2t   -> rec[0] (strip 2t),   ny=2t+1 -> rec[2] (strip 2t+1)
//   prow1 (k 128..255, bottoms):   ny=2t-1 -> rec[1] (strip 2t),   ny=2t   -> rec[3] (strip 2t+1)
__global__ __launch_bounds__(256, 3)
void patch_ae_mfma(const float* __restrict__ x, const unsigned short* __restrict__ APK,
                   const float* __restrict__ v, float* __restrict__ out) {
    // bijective XCD swizzle: 2688 blocks = 8 XCDs x 336
    const int hid = blockIdx.x + NPAIR*(blockIdx.y + 3*blockIdx.z);
    const int lid = (hid & 7)*336 + (hid >> 3);
    const int t  = lid % NPAIR;
    const int t2 = lid / NPAIR;
    const int c  = t2 % 3;
    const int b  = t2 / 3;

    const int tid  = threadIdx.x;
    const int lane = tid & 63, wave = tid >> 6;

    __shared__ __align__(16) unsigned short strip[32*264];    // image rows [16t-8,16t+24), 16896 B
    __shared__ __align__(16) unsigned short rec[4][32][136];  // 34816 B
    __shared__ __align__(16) float vsh[256];                  // 1024 B

    vsh[tid] = v[c*256 + tid];

    const int prow   = wave >> 1;
    const int kq     = wave & 1;
    const int kfbase = prow*8 + kq*4;
    const int rb0    = 8*(1 - prow);       // strip-row base for which=0 ny
    const int g = lane >> 4, lr = lane & 15;
    const s16x8* APKc = (const s16x8*)(APK + (size_t)c*65536);

    // A prefetch for jb=0 — in flight during staging
    s16x8 aNext[4];
    #pragma unroll
    for (int f = 0; f < 4; ++f) aNext[f] = APKc[((kfbase + f)*8 + 0)*64 + lane];

    // ---- stage input rows [16t-8, 16t+24) as bf16, zero-padded ----
    {
        const float* xb = x + (size_t)(b*3 + c)*IMG2;
        const int ybase = 16*t - 8;
        #pragma unroll
        for (int it = 0; it < 9; ++it) {
            int idx = tid + it*256;
            if (idx < 32*66) {
                int r  = idx / 66, c4 = idx - r*66;
                int yr = ybase + r;
                float4 xv = make_float4(0.f, 0.f, 0.f, 0.f);
                if ((unsigned)yr < IMG && c4 < 56)
                    xv = ((const float4*)(xb + (size_t)yr*IMG))[c4];
                unsigned int lo = (unsigned int)f2bf(xv.x) | ((unsigned int)f2bf(xv.y) << 16);
                unsigned int hi = (unsigned int)f2bf(xv.z) | ((unsigned int)f2bf(xv.w) << 16);
                *((uint2*)&strip[r*264 + c4*4]) = make_uint2(lo, hi);
            }
        }
    }
    __syncthreads();

    // ---- MFMA: 8 jb x {4 A-frags, 4 B-frags, 16 MFMA} ----
    {
        f32x4 acc[4][2][2];
        #pragma unroll
        for (int f = 0; f < 4; ++f)
            #pragma unroll
            for (int w = 0; w < 2; ++w)
                #pragma unroll
                for (int pf = 0; pf < 2; ++pf)
                    acc[f][w][pf] = (f32x4){0.f, 0.f, 0.f, 0.f};

        #pragma unroll
        for (int jb = 0; jb < 8; ++jb) {
            s16x8 aCur[4];
            #pragma unroll
            for (int f = 0; f < 4; ++f) aCur[f] = aNext[f];
            if (jb < 7) {
                #pragma unroll
                for (int f = 0; f < 4; ++f)
                    aNext[f] = APKc[((kfbase + f)*8 + (jb+1))*64 + lane];
            }
            const int jy  = 2*jb + (g >> 1);
            const int jx0 = (g & 1)*8;
            const unsigned short* srow = &strip[(rb0 + jy)*264 + jx0];
            s16x8 bfrag[2][2];
            #pragma unroll
            for (int w = 0; w < 2; ++w) {
                bfrag[w][0] = *((const s16x8*)&srow[w*8*264 + 8*lr]);
                bfrag[w][1] = *((const s16x8*)&srow[w*8*264 + 8*(16 + lr)]);
            }
            __builtin_amdgcn_s_setprio(1);
            #pragma unroll
            for (int f = 0; f < 4; ++f)
                #pragma unroll
                for (int w = 0; w < 2; ++w) {
                    acc[f][w][0] = __builtin_amdgcn_mfma_f32_16x16x32_bf16(aCur[f], bfrag[w][0], acc[f][w][0], 0, 0, 0);
                    acc[f][w][1] = __builtin_amdgcn_mfma_f32_16x16x32_bf16(aCur[f], bfrag[w][1], acc[f][w][1], 0, 0, 0);
                }
            __builtin_amdgcn_s_setprio(0);
        }

        // bias + bf16 store; rec[2w+prow][p][klocal], k = prow*128 + klocal
        #pragma unroll
        for (int f = 0; f < 4; ++f) {
            int klocal = kq*64 + f*16 + g*4;
            f32x4 bias = *((const f32x4*)&vsh[prow*128 + klocal]);
            #pragma unroll
            for (int w = 0; w < 2; ++w)
                #pragma unroll
                for (int pf = 0; pf < 2; ++pf) {
                    f32x4 r = acc[f][w][pf] + bias;
                    int p = pf*16 + lr;
                    unsigned int lo = (unsigned int)f2bf(r.x) | ((unsigned int)f2bf(r.y) << 16);
                    unsigned int hi = (unsigned int)f2bf(r.z) | ((unsigned int)f2bf(r.w) << 16);
                    *((uint2*)&rec[2*w + prow][p][klocal]) = make_uint2(lo, hi);
                }
        }
    }
    __syncthreads();

    // ---- combine overlaps, write 16 output rows once each (thread = column) ----
    if (tid < 224) {
        const int xc = tid;
        const int p1 = xc >> 3;
        const int v1 = (p1 <= NN-1);
        const int v0 = (p1 > 0);
        const int p0 = v0 ? p1 - 1 : 0;
        const int dx1 = xc & 7, dx0 = dx1 + 8;
        const int xsh = v0 & v1;
        float* ocol = out + (size_t)(b*3 + c)*IMG2 + (size_t)(16*t)*IMG + xc;
        #pragma unroll
        for (int sl = 0; sl < 2; ++sl) {
            const int hT = (sl == 0) ? 1 : (t < NPAIR-1);   // top patch-row exists
            const int hB = (sl == 0) ? (t > 0) : 1;         // bottom patch-row exists
            const int rT = 2*sl, rB = 2*sl + 1;
            const int shift = xsh + (hT & hB);
            const float inv = __int_as_float(0x3f800000 - (shift << 23)); // exact 1/2^shift
            #pragma unroll
            for (int r = 0; r < 8; ++r) {
                int kl1 = r*16 + dx1, kl0 = r*16 + dx0;
                float sum = 0.f;
                if (v1) {
                    if (hT) sum += bf2f(rec[rT][p1][kl1]);
                    if (hB) sum += bf2f(rec[rB][p1][kl1]);
                }
                if (v0) {
                    if (hT) sum += bf2f(rec[rT][p0][kl0]);
                    if (hB) sum += bf2f(rec[rB][p0][kl0]);
                }
                ocol[(size_t)(sl*8 + r)*IMG] = sum * inv;
            }
        }
    }
}

extern "C" void kernel_launch(void* const* d_in, const int* in_sizes, int n_in,
                              void* d_out, int out_size, void* d_ws, size_t ws_size,
                              hipStream_t stream) {
    (void)in_sizes; (void)n_in; (void)out_size; (void)ws_size;
    const float* x     = (const float*)d_in[0];
    const float* W_enc = (const float*)d_in[1];
    const float* b_enc = (const float*)d_in[2];
    const float* W_dec = (const float*)d_in[3];
    const float* b_dec = (const float*)d_in[4];
    float* out = (float*)d_out;

    float*          v   = (float*)d_ws;                          // 768 f32
    unsigned short* APK = (unsigned short*)((char*)d_ws + 4096); // 3 x 65536 bf16 = 384 KB

    pack_M<<<dim3(KK, 3), 256, 0, stream>>>(W_enc, W_dec, b_enc, b_dec, APK, v);
    patch_ae_mfma<<<dim3(NPAIR, 3, 64), 256, 0, stream>>>(x, APK, v, out);
}